// Round 9
// baseline (88.994 us; speedup 1.0000x reference)
//
#include <hip/hip_runtime.h>
#include <hip/hip_bf16.h>

typedef __bf16 bf16x8 __attribute__((ext_vector_type(8)));
typedef float  f32x4  __attribute__((ext_vector_type(4)));

#define B_SZ 1024
#define D_SZ 128
#define C_SZ 100000
#define CPAD 100096          // padded class rows (zero tail), 6256*16
#define NG   256             // col-stream groups (grid.x)
#define NCT16 6256           // 100096/16 col tiles
#define TSTRIDE (NG * 4096)  // bytes between consecutive tiles of one stream

#define SCALE_F   64.0f
#define MARGIN_F  0.35f
#define CLIP_F    (1.0f - 1e-7f)
#define LOG2E_F   1.4426950408889634f
#define S_LOG2E_F (64.0f * 1.4426950408889634f)

// ---- Kernel A: L2-normalize W rows -> bf16 (+zero pad) + convert E -> bf16.
__global__ void norm_conv(const float* __restrict__ W, __bf16* __restrict__ Wb,
                          const float* __restrict__ E, __bf16* __restrict__ Eb) {
    const int b = blockIdx.x;
    if (b < 12512) {
        const int lane = threadIdx.x & 63;
        const int l32  = lane & 31;
        const int row  = b * 8 + ((threadIdx.x >> 6) << 1) + (lane >> 5);
        if (row < C_SZ) {
            float4 v = reinterpret_cast<const float4*>(W + (size_t)row * D_SZ)[l32];
            float ss = v.x * v.x + v.y * v.y + v.z * v.z + v.w * v.w;
            #pragma unroll
            for (int m = 1; m < 32; m <<= 1) ss += __shfl_xor(ss, m);
            float sc = 1.0f / fmaxf(sqrtf(ss), 1e-12f);
            union { __bf16 h[4]; uint2 u; } o;
            o.h[0] = (__bf16)(v.x * sc); o.h[1] = (__bf16)(v.y * sc);
            o.h[2] = (__bf16)(v.z * sc); o.h[3] = (__bf16)(v.w * sc);
            reinterpret_cast<uint2*>(Wb + (size_t)row * D_SZ)[l32] = o.u;
        } else {   // zero pad rows [C_SZ, CPAD)
            uint2 z; z.x = 0u; z.y = 0u;
            reinterpret_cast<uint2*>(Wb + (size_t)row * D_SZ)[l32] = z;
        }
    } else {
        const int i = (b - 12512) * 256 + threadIdx.x;   // 32768 float4
        float4 v = reinterpret_cast<const float4*>(E)[i];
        union { __bf16 h[4]; uint2 u; } o;
        o.h[0] = (__bf16)v.x; o.h[1] = (__bf16)v.y;
        o.h[2] = (__bf16)v.z; o.h[3] = (__bf16)v.w;
        reinterpret_cast<uint2*>(Eb)[i] = o.u;
    }
}

// ---- Kernel C: LDS-free fused GEMM + exp-sum.
// grid = (NG=256 col-streams, 4 row-groups), 256 thr = 4 independent waves.
// Per wave: 64 E-rows (a-frags in regs) x a stream of 16-class tiles read
// DIRECTLY from global (B tile 4KB, L1-resident; 16x64B fully-coalesced
// fragment loads). No LDS, no barriers, no waitcnt games: TLP + register
// prefetch (bn) hide L2 latency. Regs ~130 -> (256,3) cap, no spill.
__launch_bounds__(256, 3)
__global__ void gemm_lse(const __bf16* __restrict__ Eb, const __bf16* __restrict__ Wb,
                         float* __restrict__ P) {
    const int tid  = threadIdx.x;
    const int wave = tid >> 6;            // 0..3 : 64-row slice
    const int lane = tid & 63;
    const int g4   = lane >> 4;
    const int l15  = lane & 15;
    const int g    = blockIdx.x;          // 0..255 col stream
    const int rg   = blockIdx.y;          // 0..3  row group (256 rows)

    const int T = (NCT16 - g + NG - 1) / NG;   // 25 for g<112, else 24

    // ---- A fragments (once): rows rg*256 + wave*64 + mi*16 + l15
    bf16x8 a[4][4];
    {
        const char* ebase = reinterpret_cast<const char*>(Eb)
                          + (size_t)(rg * 256 + wave * 64) * 256;
        #pragma unroll
        for (int mi = 0; mi < 4; ++mi) {
            const char* pr = ebase + (mi * 16 + l15) * 256 + g4 * 16;
            #pragma unroll
            for (int kk = 0; kk < 4; ++kk)
                a[mi][kk] = *reinterpret_cast<const bf16x8*>(pr + kk * 64);
        }
    }

    // B fragment pointer: class row = ct*16 + l15, bytes kk*64 + g4*16
    const char* pB = reinterpret_cast<const char*>(Wb)
                   + (size_t)g * 4096 + l15 * 256 + g4 * 16;

    float rowsum[4][4] = {};   // [mi][r]

    // prologue: load tile 0
    bf16x8 b[4];
    #pragma unroll
    for (int kk = 0; kk < 4; ++kk)
        b[kk] = *reinterpret_cast<const bf16x8*>(pB + kk * 64);
    pB += TSTRIDE;

    for (int t = 0; t < T; ++t) {
        // prefetch next tile while computing current
        bf16x8 bn[4];
        if (t + 1 < T) {
            #pragma unroll
            for (int kk = 0; kk < 4; ++kk)
                bn[kk] = *reinterpret_cast<const bf16x8*>(pB + kk * 64);
            pB += TSTRIDE;
        }

        f32x4 acc[4] = {};
        #pragma unroll
        for (int kk = 0; kk < 4; ++kk)
            #pragma unroll
            for (int mi = 0; mi < 4; ++mi)
                acc[mi] = __builtin_amdgcn_mfma_f32_16x16x32_bf16(
                    a[mi][kk], b[kk], acc[mi], 0, 0, 0);

        // epilogue: rowsum += exp2(min(x*92.33 - 92.33, 0)).
        // Lower clip free (underflow to 0); upper clip = the fmin (needed:
        // unnormalized E gives |dot| up to ~6 -> arg would overflow).
        #pragma unroll
        for (int mi = 0; mi < 4; ++mi)
            #pragma unroll
            for (int r = 0; r < 4; ++r)
                rowsum[mi][r] += __builtin_amdgcn_exp2f(
                    fminf(fmaf(acc[mi][r], S_LOG2E_F, -S_LOG2E_F), 0.0f));

        #pragma unroll
        for (int kk = 0; kk < 4; ++kk) b[kk] = bn[kk];
    }

    // ---- reduce across the 16 l15-lanes (cols), then store 64 row-partials
    #pragma unroll
    for (int mi = 0; mi < 4; ++mi) {
        #pragma unroll
        for (int r = 0; r < 4; ++r) {
            float s = rowsum[mi][r];
            s += __shfl_xor(s, 1);
            s += __shfl_xor(s, 2);
            s += __shfl_xor(s, 4);
            s += __shfl_xor(s, 8);
            rowsum[mi][r] = s;
        }
    }
    if (l15 == 0) {
        const int rowbase = rg * 256 + wave * 64;
        #pragma unroll
        for (int mi = 0; mi < 4; ++mi)
            #pragma unroll
            for (int r = 0; r < 4; ++r)
                P[(size_t)g * B_SZ + rowbase + mi * 16 + g4 * 4 + r] = rowsum[mi][r];
    }
}

// ---- Kernel D1: per-row S reduce (NG=256 partials) + target dot + nll
__global__ void row_fin(const float* __restrict__ P, const __bf16* __restrict__ Eb,
                        const __bf16* __restrict__ Wb, const int* __restrict__ lab,
                        float* __restrict__ nll) {
    __shared__ float red[256];
    const int row = blockIdx.x;
    const int t   = threadIdx.x;

    red[t] = P[(size_t)t * B_SZ + row];
    __syncthreads();
    #pragma unroll
    for (int off = 128; off > 0; off >>= 1) {
        if (t < off) red[t] += red[t + off];
        __syncthreads();
    }
    const float S = red[0];
    __syncthreads();

    const int lb = lab[row];
    float d = 0.0f;
    if (t < 128) d = (float)Eb[row * D_SZ + t] * (float)Wb[(size_t)lb * D_SZ + t];
    red[t] = d;
    __syncthreads();
    #pragma unroll
    for (int off = 128; off > 0; off >>= 1) {
        if (t < off) red[t] += red[t + off];
        __syncthreads();
    }

    if (t == 0) {
        const float ct = red[0];
        const float cc = fminf(fmaxf(ct, -CLIP_F), CLIP_F);
        const float lt = SCALE_F * (cc - MARGIN_F);
        float Sadj = S - exp2f((SCALE_F * cc - SCALE_F) * LOG2E_F)
                       + exp2f((lt - SCALE_F) * LOG2E_F);
        nll[row] = SCALE_F + logf(Sadj) - lt;
    }
}

// ---- Kernel D2: mean over 1024 rows (shuffle-based)
__global__ void mean_k(const float* __restrict__ nll, float* __restrict__ out) {
    __shared__ float part[16];
    const int t = threadIdx.x;
    float v = nll[t];
    #pragma unroll
    for (int m = 1; m < 64; m <<= 1) v += __shfl_xor(v, m);
    if ((t & 63) == 0) part[t >> 6] = v;
    __syncthreads();
    if (t < 16) {
        float u = part[t];
        #pragma unroll
        for (int m = 1; m < 16; m <<= 1) u += __shfl_xor(u, m);
        if (t == 0) out[0] = u * (1.0f / 1024.0f);
    }
}

extern "C" void kernel_launch(void* const* d_in, const int* in_sizes, int n_in,
                              void* d_out, int out_size, void* d_ws, size_t ws_size,
                              hipStream_t stream) {
    const float* E   = (const float*)d_in[0];
    const int*   lab = (const int*)d_in[1];
    const float* W   = (const float*)d_in[2];
    float*       out = (float*)d_out;

    char* ws = (char*)d_ws;
    __bf16* Eb  = (__bf16*)ws;                                   // 262,144 B
    __bf16* Wb  = (__bf16*)(ws + 262144);                        // 25,624,576 B (CPAD rows)
    float*  P   = (float*)(ws + 262144 + 25624576);              // 1,048,576 B
    float*  nll = (float*)(ws + 262144 + 25624576 + 1048576);    // 4,096 B

    norm_conv<<<dim3(12640),   256, 0, stream>>>(W, Wb, E, Eb);
    gemm_lse <<<dim3(NG, 4),   256, 0, stream>>>(Eb, Wb, P);
    row_fin  <<<dim3(B_SZ),    256, 0, stream>>>(P, Eb, Wb, lab, nll);
    mean_k   <<<dim3(1),      1024, 0, stream>>>(nll, out);
}

// Round 10
// 65.209 us; speedup vs baseline: 1.3647x; 1.3647x over previous
//
#include <hip/hip_runtime.h>
#include <hip/hip_bf16.h>

typedef __bf16 bf16x8 __attribute__((ext_vector_type(8)));
typedef float  f32x16 __attribute__((ext_vector_type(16)));

#define B_SZ 1024
#define D_SZ 128
#define C_SZ 100000
#define CPAD 100096          // padded class rows (zero tail), 782*128
#define BM 128
#define BN 128
#define NG 64                // C-tile groups (grid.x)
#define NCT 782              // 100096/128

#define SCALE_F   64.0f
#define MARGIN_F  0.35f
#define CLIP_F    (1.0f - 1e-7f)
#define LOG2E_F   1.4426950408889634f
#define S_LOG2E_F (64.0f * 1.4426950408889634f)

__device__ __forceinline__ void gload_lds16(const void* g, void* l) {
    __builtin_amdgcn_global_load_lds(
        (const __attribute__((address_space(1))) void*)g,
        (__attribute__((address_space(3))) void*)l, 16, 0, 0);
}

// ---- Kernel A: L2-normalize W rows -> bf16 (+zero pad) + convert E -> bf16.
__global__ void norm_conv(const float* __restrict__ W, __bf16* __restrict__ Wb,
                          const float* __restrict__ E, __bf16* __restrict__ Eb) {
    const int b = blockIdx.x;
    if (b < 12512) {
        const int lane = threadIdx.x & 63;
        const int l32  = lane & 31;
        const int row  = b * 8 + ((threadIdx.x >> 6) << 1) + (lane >> 5);
        if (row < C_SZ) {
            float4 v = reinterpret_cast<const float4*>(W + (size_t)row * D_SZ)[l32];
            float ss = v.x * v.x + v.y * v.y + v.z * v.z + v.w * v.w;
            #pragma unroll
            for (int m = 1; m < 32; m <<= 1) ss += __shfl_xor(ss, m);
            float sc = 1.0f / fmaxf(sqrtf(ss), 1e-12f);
            union { __bf16 h[4]; uint2 u; } o;
            o.h[0] = (__bf16)(v.x * sc); o.h[1] = (__bf16)(v.y * sc);
            o.h[2] = (__bf16)(v.z * sc); o.h[3] = (__bf16)(v.w * sc);
            reinterpret_cast<uint2*>(Wb + (size_t)row * D_SZ)[l32] = o.u;
        } else {   // zero pad rows [C_SZ, CPAD)
            uint2 z; z.x = 0u; z.y = 0u;
            reinterpret_cast<uint2*>(Wb + (size_t)row * D_SZ)[l32] = z;
        }
    } else {
        const int i = (b - 12512) * 256 + threadIdx.x;   // 32768 float4
        float4 v = reinterpret_cast<const float4*>(E)[i];
        union { __bf16 h[4]; uint2 u; } o;
        o.h[0] = (__bf16)v.x; o.h[1] = (__bf16)v.y;
        o.h[2] = (__bf16)v.z; o.h[3] = (__bf16)v.w;
        reinterpret_cast<uint2*>(Eb)[i] = o.u;
    }
}

// ---- Kernel C: fused GEMM + exp-sum. R4 skeleton + 32x32x16 MFMA + chunked LDS.
// grid = (NG=64, 8 bi), 512 thr = 8 waves (4wm x 2wn); wave tile 32 rows x 64 cols.
// LDS B layout: [chunk cs=ks*2+h][col][8 bf16] (2KB per chunk, 16 chunks/tile).
//   - ds_read: lane l reads chunk (ks*2 + (l>>5)) at col*16: 32 consecutive
//     16B within 512B -> conflict-free; address = lane-const + imm offset.
//   - staging: linear LDS dest, chunk permutation folded into global source
//     (both-sides rule): src = (tid&127)*256 + ((tid>>7) + j*4)*16.
// MFMA: v_mfma_f32_32x32x16_bf16, 16 per tile (2x FLOP/inst vs 16x16x32).
__launch_bounds__(512, 3)
__global__ void gemm_lse(const __bf16* __restrict__ Eb, const __bf16* __restrict__ Wb,
                         float* __restrict__ P) {
    __shared__ __bf16 sB[2][BN * D_SZ];   // 2 x 32 KB chunked
    __shared__ float  rs[2][BM];          // 1 KB cross-wave reduce

    const int tid  = threadIdx.x;
    const int wave = tid >> 6;
    const int lane = tid & 63;
    const int l31  = lane & 31;
    const int h    = lane >> 5;           // k-half select
    const int wm   = wave >> 1;           // 0..3 : 32-row slice
    const int wn   = wave & 1;            // 0..1 : 64-col slice
    const int g    = blockIdx.x;          // 0..63
    const int bi   = blockIdx.y;          // 0..7

    const int T = (NCT - g + NG - 1) / NG;   // 13 for g<14, else 12

    const char* wbase = reinterpret_cast<const char*>(Wb);
    // staging source (pre-permuted for chunked layout), pass-invariant part
    const int srcOff = ((tid & 127) << 8) + ((tid >> 7) << 4);
    const int ldsOff = wave << 10;        // wave-uniform dest base within 8KB pass

#define STAGE(TI, BUF)                                                          \
    {                                                                           \
        const char* _s = wbase + (size_t)(TI) * 32768 + srcOff;                 \
        char* _d = reinterpret_cast<char*>(BUF) + ldsOff;                       \
        _Pragma("unroll")                                                       \
        for (int j = 0; j < 4; ++j)                                             \
            gload_lds16(_s + (j << 6), _d + j * 8192);                          \
    }

    // ---- stage first B tile
    STAGE(g, sB[0]);

    // ---- A fragments straight from global (once): row = wm*32+l31,
    // k-bytes = ks*32 + h*16.  8 x 16B = 32 VGPR.
    bf16x8 a[8];
    {
        const char* pr = reinterpret_cast<const char*>(Eb)
                       + ((size_t)bi * BM + wm * 32 + l31) * 256 + h * 16;
        #pragma unroll
        for (int ks = 0; ks < 8; ++ks)
            a[ks] = *reinterpret_cast<const bf16x8*>(pr + ks * 32);
    }

    // per-lane B base: chunk h, col = wn*64 + l31  (nj adds 512, ks adds 4096)
    const int bOff = h * 2048 + (wn * 64 + l31) * 16;

    float rowsum[16] = {};

    __syncthreads();

    int cur = 0;
    for (int t = 0; t < T; ++t) {
        if (t + 1 < T) STAGE(g + (t + 1) * NG, sB[cur ^ 1]);

        const char* sBb = reinterpret_cast<const char*>(sB[cur]) + bOff;
        f32x16 ac0 = {}, ac1 = {};
        #pragma unroll
        for (int ks = 0; ks < 8; ++ks) {
            bf16x8 b0 = *reinterpret_cast<const bf16x8*>(sBb + ks * 4096);
            bf16x8 b1 = *reinterpret_cast<const bf16x8*>(sBb + ks * 4096 + 512);
            ac0 = __builtin_amdgcn_mfma_f32_32x32x16_bf16(a[ks], b0, ac0, 0, 0, 0);
            ac1 = __builtin_amdgcn_mfma_f32_32x32x16_bf16(a[ks], b1, ac1, 0, 0, 0);
        }

        // epilogue: rowsum += exp2(min(x*92.33 - 92.33, 0)) for both col-groups.
        // Lower clip free (underflow); upper clip = the fmin (needed: unnormalized
        // E gives |dot| up to ~6 -> arg would overflow).
        #pragma unroll
        for (int i = 0; i < 16; ++i) {
            float s0 = __builtin_amdgcn_exp2f(
                fminf(fmaf(ac0[i], S_LOG2E_F, -S_LOG2E_F), 0.0f));
            float s1 = __builtin_amdgcn_exp2f(
                fminf(fmaf(ac1[i], S_LOG2E_F, -S_LOG2E_F), 0.0f));
            rowsum[i] += s0 + s1;
        }
        __syncthreads();   // prefetch landed; cur buffer free
        cur ^= 1;
    }

    // ---- reduce across 32 col-lanes (each h-half independently)
    #pragma unroll
    for (int i = 0; i < 16; ++i) {
        float s = rowsum[i];
        s += __shfl_xor(s, 1);
        s += __shfl_xor(s, 2);
        s += __shfl_xor(s, 4);
        s += __shfl_xor(s, 8);
        s += __shfl_xor(s, 16);
        rowsum[i] = s;
    }
    if (l31 == 0) {
        // acc slot i -> local row (i&3) + 8*(i>>2) + 4*h
        #pragma unroll
        for (int i = 0; i < 16; ++i)
            rs[wn][wm * 32 + (i & 3) + 8 * (i >> 2) + 4 * h] = rowsum[i];
    }
    __syncthreads();
    if (tid < BM)
        P[(size_t)g * B_SZ + bi * BM + tid] = rs[0][tid] + rs[1][tid];
#undef STAGE
}

// ---- Kernel D1: per-row S reduce (NG=64 partials) + target dot + nll
__global__ void row_fin(const float* __restrict__ P, const __bf16* __restrict__ Eb,
                        const __bf16* __restrict__ Wb, const int* __restrict__ lab,
                        float* __restrict__ nll) {
    __shared__ float red[256];
    const int row = blockIdx.x;
    const int t   = threadIdx.x;

    red[t] = (t < NG) ? P[(size_t)t * B_SZ + row] : 0.0f;
    __syncthreads();
    #pragma unroll
    for (int off = 128; off > 0; off >>= 1) {
        if (t < off) red[t] += red[t + off];
        __syncthreads();
    }
    const float S = red[0];
    __syncthreads();

    const int lb = lab[row];
    float d = 0.0f;
    if (t < 128) d = (float)Eb[row * D_SZ + t] * (float)Wb[(size_t)lb * D_SZ + t];
    red[t] = d;
    __syncthreads();
    #pragma unroll
    for (int off = 128; off > 0; off >>= 1) {
        if (t < off) red[t] += red[t + off];
        __syncthreads();
    }

    if (t == 0) {
        const float ct = red[0];
        const float cc = fminf(fmaxf(ct, -CLIP_F), CLIP_F);
        const float lt = SCALE_F * (cc - MARGIN_F);
        float Sadj = S - exp2f((SCALE_F * cc - SCALE_F) * LOG2E_F)
                       + exp2f((lt - SCALE_F) * LOG2E_F);
        nll[row] = SCALE_F + logf(Sadj) - lt;
    }
}

// ---- Kernel D2: mean over 1024 rows (shuffle-based)
__global__ void mean_k(const float* __restrict__ nll, float* __restrict__ out) {
    __shared__ float part[16];
    const int t = threadIdx.x;
    float v = nll[t];
    #pragma unroll
    for (int m = 1; m < 64; m <<= 1) v += __shfl_xor(v, m);
    if ((t & 63) == 0) part[t >> 6] = v;
    __syncthreads();
    if (t < 16) {
        float u = part[t];
        #pragma unroll
        for (int m = 1; m < 16; m <<= 1) u += __shfl_xor(u, m);
        if (t == 0) out[0] = u * (1.0f / 1024.0f);
    }
}

extern "C" void kernel_launch(void* const* d_in, const int* in_sizes, int n_in,
                              void* d_out, int out_size, void* d_ws, size_t ws_size,
                              hipStream_t stream) {
    const float* E   = (const float*)d_in[0];
    const int*   lab = (const int*)d_in[1];
    const float* W   = (const float*)d_in[2];
    float*       out = (float*)d_out;

    char* ws = (char*)d_ws;
    __bf16* Eb  = (__bf16*)ws;                                   // 262,144 B
    __bf16* Wb  = (__bf16*)(ws + 262144);                        // 25,624,576 B (CPAD rows)
    float*  P   = (float*)(ws + 262144 + 25624576);              // 262,144 B
    float*  nll = (float*)(ws + 262144 + 25624576 + 262144);     // 4,096 B

    norm_conv<<<dim3(12640),   256, 0, stream>>>(W, Wb, E, Eb);
    gemm_lse <<<dim3(NG, 8),   512, 0, stream>>>(Eb, Wb, P);
    row_fin  <<<dim3(B_SZ),    256, 0, stream>>>(P, Eb, Wb, lab, nll);
    mean_k   <<<dim3(1),      1024, 0, stream>>>(nll, out);
}